// Round 8
// baseline (268.582 us; speedup 1.0000x reference)
//
#include <hip/hip_runtime.h>
#include <hip/hip_bf16.h>
#include <cstdint>

#define H 1024
#define BSZ 4
#define LSEQ 2048
#define M_TOT (BSZ*LSEQ)   // 8192
#define NCH2 128           // 16-row L-chunks per batch for the delta scan
#define LCH2 16

typedef __attribute__((ext_vector_type(4))) float  f32x4;
typedef __attribute__((ext_vector_type(2))) float  f32x2;
typedef __attribute__((ext_vector_type(8))) __bf16 bf16x8;
typedef __attribute__((ext_vector_type(4))) __bf16 bf16x4;
typedef __attribute__((ext_vector_type(2))) __bf16 bf16x2;

typedef __attribute__((address_space(1))) unsigned int as1_u32;
typedef __attribute__((address_space(3))) unsigned int as3_u32;

__device__ __forceinline__ void gld_lds16(const void* g, const void* l) {
    as1_u32* gp = reinterpret_cast<as1_u32*>((uintptr_t)g);
    as3_u32* lp = reinterpret_cast<as3_u32*>((uint32_t)(uintptr_t)l);
    __builtin_amdgcn_global_load_lds(gp, lp, 16, 0, 0);
}

// fast softplus: stable, native exp/log
__device__ __forceinline__ float softplus_fast(float f) {
    return fmaxf(f, 0.f) + __logf(1.f + __expf(-fabsf(f)));
}

#define BAR()    asm volatile("s_barrier" ::: "memory")
#define WAIT4()  asm volatile("s_waitcnt vmcnt(4)" ::: "memory")
#define WAIT0()  asm volatile("s_waitcnt vmcnt(0)" ::: "memory")

// ---------------- Wfuse = Wd @ Wp1 : 64x64 tiles, 256 blocks ----------------
__global__ __launch_bounds__(256) void wfuse_gemm(
    const __bf16* __restrict__ A,
    const __bf16* __restrict__ B,
    __bf16* __restrict__ O)
{
    __shared__ __align__(16) __bf16 lds[2*4096];
    const int tid  = threadIdx.x;
    const int lane = tid & 63;
    const int wid  = tid >> 6;
    const int l15  = lane & 15;
    const int quad = lane >> 4;
    const int row0 = blockIdx.y * 64;
    const int col0 = blockIdx.x * 64;

    const __bf16* Asrc = A + (size_t)(row0 + (tid >> 2)) * 1024 + (tid & 3) * 8;
    const __bf16* Bsrc = B + (size_t)(col0 + (tid >> 2)) * 1024 + (tid & 3) * 8;
    const int ldst = (tid >> 2) * 32 + (tid & 3) * 8;   // = tid*8 (linear)

    auto stage = [&](int buf, int kt) {
        gld_lds16(Asrc + kt * 32, lds + buf * 4096 + ldst);
        gld_lds16(Bsrc + kt * 32, lds + buf * 4096 + 2048 + ldst);
    };

    f32x4 acc[4] = {};
    stage(0, 0);
#pragma unroll 2
    for (int kt = 0; kt < 32; ++kt) {
        __syncthreads();                         // implicit vmcnt/lgkm drain
        if (kt + 1 < 32) stage((kt + 1) & 1, kt + 1);
        const __bf16* base = lds + (kt & 1) * 4096;
        bf16x8 a = *(const bf16x8*)(base + (wid * 16 + l15) * 32 + quad * 8);
        bf16x8 b[4];
#pragma unroll
        for (int j = 0; j < 4; ++j)
            b[j] = *(const bf16x8*)(base + 2048 + (j * 16 + l15) * 32 + quad * 8);
#pragma unroll
        for (int j = 0; j < 4; ++j)
            acc[j] = __builtin_amdgcn_mfma_f32_16x16x32_bf16(a, b[j], acc[j], 0, 0, 0);
    }

    const int rowb = row0 + wid * 16 + quad * 4;
#pragma unroll
    for (int j = 0; j < 4; ++j) {
        const int col = col0 + j * 16 + l15;
#pragma unroll
        for (int r = 0; r < 4; ++r)
            O[(size_t)(rowb + r) * H + col] = (__bf16)acc[j][r];
    }
}

// ---------------- BIG GEMM: 256x128 tile, BK=64, 768 blocks -----------------
// R5 skeleton (one barrier/tile, counted waits) with round-8 change:
// B BYPASSES LDS. A: 3-buffer LDS rotation (32KB/buf, 96KB total), staged
// via global_load_lds with granule XOR (pre-swizzled source). B: each wave
// loads its 8 b128 fragments per tile DIRECTLY from global (L2/LLC-resident,
// 6MB) into registers, double-buffered bfP/bfQ (static indices only).
// This moves B's 16KB stage + 64KB read per tile OFF the LDS port
// (2120 -> ~1155 cy/tile LDS) onto the parallel vector-mem path.
// Ledger (vmcnt counts gld_lds AND B reg-loads in issue order; order pinned
// by compiler barriers): per iter issue [8 B(t+1)] then [4 A-stage(t+2)].
// Queue entering tile t: [A(t):4, B(t):8, A(t+1):4] -> WAIT4 retires exactly
// A(t)+B(t). Prologue [A0, B0, A1]; t15 enters with [A15, B15] -> WAIT0.
// A-stage target (t+2)%3 is disjoint from read buf t%3 and (t+1)%3.

#define STA4(b,kt) do {                                                       \
    gld_lds16(Asrc + (size_t)  0*H + (kt)*64, lds + (b)*16384 +         lwb); \
    gld_lds16(Asrc + (size_t) 64*H + (kt)*64, lds + (b)*16384 +  4096 + lwb); \
    gld_lds16(Asrc + (size_t)128*H + (kt)*64, lds + (b)*16384 +  8192 + lwb); \
    gld_lds16(Asrc + (size_t)192*H + (kt)*64, lds + (b)*16384 + 12288 + lwb); \
} while(0)

#define BLOAD(dst, kt) do {                                                   \
    _Pragma("unroll")                                                         \
    for (int j_ = 0; j_ < 4; ++j_) {                                          \
        dst[j_]     = *(const bf16x8*)(Bpj[j_] + (kt)*64);                    \
        dst[4 + j_] = *(const bf16x8*)(Bpj[j_] + (kt)*64 + 32);               \
    }                                                                         \
} while(0)

#define TILEB(bc,bn,kn, BC, BN, knB, DB_, DS, WAITMAC) do {                   \
    WAITMAC();                                                                \
    BAR();                                                                    \
    { const __bf16* base_ = lds + (bc)*16384;                                 \
      _Pragma("unroll")                                                       \
      for (int i_ = 0; i_ < 4; ++i_) {                                        \
          af0[i_] = *(const bf16x8*)(base_ + aoff[i_]);                       \
          af1[i_] = *(const bf16x8*)(base_ + (aoff[i_] ^ 32));                \
      } }                                                                     \
    if (DB_) BLOAD(BN, knB);                                                  \
    asm volatile("" ::: "memory");  /* pin B-issue before A-stage (ledger) */ \
    if (DS) STA4(bn, kn);                                                     \
    __builtin_amdgcn_s_setprio(1);                                            \
    _Pragma("unroll")                                                         \
    for (int i_ = 0; i_ < 4; ++i_)                                            \
    _Pragma("unroll")                                                         \
    for (int j_ = 0; j_ < 4; ++j_)                                            \
        acc[i_][j_] = __builtin_amdgcn_mfma_f32_16x16x32_bf16(                \
            af0[i_], BC[j_], acc[i_][j_], 0, 0, 0);                           \
    _Pragma("unroll")                                                         \
    for (int i_ = 0; i_ < 4; ++i_)                                            \
    _Pragma("unroll")                                                         \
    for (int j_ = 0; j_ < 4; ++j_)                                            \
        acc[i_][j_] = __builtin_amdgcn_mfma_f32_16x16x32_bf16(                \
            af1[i_], BC[4 + j_], acc[i_][j_], 0, 0, 0);                       \
    __builtin_amdgcn_s_setprio(0);                                            \
} while(0)

__global__ __launch_bounds__(512, 2) void gemm256b(
    const __bf16* __restrict__ A,
    const __bf16* __restrict__ B,
    __bf16* __restrict__ O0,
    __bf16* __restrict__ O2,
    const __bf16* __restrict__ xb,
    const float* __restrict__ bias,
    float* __restrict__ pD,     // [512][1024] 16-row chunk col sums
    float* __restrict__ pUp,    // [64][1024] partial sum(x*Cs) per 128-row blk
    float* __restrict__ pCp)    // [64][1024] partial sum(Cs)
{
    __shared__ __align__(16) __bf16 lds[49152];   // 96 KiB: 3 x A[256][64]

    const int tid  = threadIdx.x;
    const int lane = tid & 63;
    const int wid  = tid >> 6;
    const int l15  = lane & 15;
    const int quad = lane >> 4;
    const int wrv  = (wid >> 1) * 64;   // 4 M-strips of 64 rows
    const int wcv  = (wid & 1) * 64;    // 2 N-strips of 64 cols

    // XCD-bijective swizzle: 768 blocks, 768 % 8 == 0
    const int bid = blockIdx.x;
    const int swz = (bid & 7) * 96 + (bid >> 3);
    const int bx = swz % 24;            // 24 col-blocks of 128
    const int by = swz / 24;            // 32 row-blocks of 256
    const int row0 = by * 256;
    const int col0 = bx * 128;

    // A staging: pre-swizzled global granule, linear LDS dest (rule 21)
    const int lg = (tid & 7) ^ ((tid >> 3) & 7);
    const __bf16* Asrc = A + (size_t)(row0 + (tid >> 3)) * H + lg * 8;
    const int lwb = wid * 512;          // wave-uniform LDS base (elements)

    // A ds_read offsets (XOR unswizzle)
    int aoff[4];
#pragma unroll
    for (int i = 0; i < 4; ++i)
        aoff[i] = (wrv + i*16 + l15)*64 + ((quad ^ (l15 & 7)) << 3);

    // B direct-from-global fragment pointers (no swizzle; L2/LLC-resident)
    const __bf16* Bp0 = B + (size_t)(col0 + wcv + l15) * H + quad*8;
    const __bf16* Bpj[4] = { Bp0, Bp0 + 16*H, Bp0 + 32*H, Bp0 + 48*H };

    f32x4 acc[4][4] = {};
    bf16x8 af0[4], af1[4];
    bf16x8 bfP[8], bfQ[8];

    // prologue: [A(0):4, B(0):8, A(1):4]
    STA4(0, 0);
    asm volatile("" ::: "memory");
    BLOAD(bfP, 0);
    asm volatile("" ::: "memory");
    STA4(1, 1);

#pragma unroll 1
    for (int g = 0; g < 2; ++g) {
        TILEB(0, 2, 6*g + 2, bfP, bfQ, 6*g + 1, 1, 1, WAIT4);   // t = 6g
        TILEB(1, 0, 6*g + 3, bfQ, bfP, 6*g + 2, 1, 1, WAIT4);   // t = 6g+1
        TILEB(2, 1, 6*g + 4, bfP, bfQ, 6*g + 3, 1, 1, WAIT4);   // t = 6g+2
        TILEB(0, 2, 6*g + 5, bfQ, bfP, 6*g + 4, 1, 1, WAIT4);   // t = 6g+3
        TILEB(1, 0, 6*g + 6, bfP, bfQ, 6*g + 5, 1, 1, WAIT4);   // t = 6g+4
        TILEB(2, 1, 6*g + 7, bfQ, bfP, 6*g + 6, 1, 1, WAIT4);   // t = 6g+5
    }
    TILEB(0, 2, 14, bfP, bfQ, 13, 1, 1, WAIT4);   // t12
    TILEB(1, 0, 15, bfQ, bfP, 14, 1, 1, WAIT4);   // t13
    TILEB(2, 0,  0, bfP, bfQ, 15, 1, 0, WAIT4);   // t14 (no A-stage)
    TILEB(0, 0,  0, bfQ, bfP,  0, 0, 0, WAIT0);   // t15 (drain)
    __syncthreads();

    // ---------------- epilogue ----------------
    const int seg   = col0 >> 10;
    const int cbase = col0 & 1023;
    const int colb  = cbase + wcv + l15;
    const int rowb  = row0 + wrv + quad*4;

    if (seg == 0) {
        // delta: bias + softplus + store + per-16-row-chunk col sums
        const int chunk16 = (row0 + wrv) >> 4;   // global 16-row chunk base
#pragma unroll
        for (int j = 0; j < 4; ++j) {
            const int col = colb + j*16;
            const float bv = bias[col];
#pragma unroll
            for (int i = 0; i < 4; ++i) {
                float s = 0.f;
#pragma unroll
                for (int r = 0; r < 4; ++r) {
                    float f = softplus_fast(acc[i][j][r] + bv);
                    O0[(size_t)(rowb + i*16 + r) * H + col] = (__bf16)f;
                    s += f;
                }
                s += __shfl_down(s, 32); s += __shfl_down(s, 16);
                if (quad == 0) pD[(size_t)(chunk16 + i)*H + col] = s;
            }
        }
    } else if (seg == 2) {
        // residual: plain store
#pragma unroll
        for (int i = 0; i < 4; ++i)
#pragma unroll
            for (int j = 0; j < 4; ++j) {
                const int col = colb + j*16;
#pragma unroll
                for (int r = 0; r < 4; ++r)
                    O2[(size_t)(rowb + i*16 + r) * H + col] = (__bf16)acc[i][j][r];
            }
    } else {
        // Cs: 256x128 tile -> LDS (granule-XOR), coalesced reduce with xb,
        // cross-group reduce -> pUp/pCp[64][1024] (per-128-row partials).
#pragma unroll
        for (int i = 0; i < 4; ++i)
#pragma unroll
            for (int j = 0; j < 4; ++j) {
                const int lcol = wcv + j*16 + l15;
#pragma unroll
                for (int r = 0; r < 4; ++r) {
                    const int lrow = wrv + i*16 + quad*4 + r;
                    lds[lrow*128 + (((lcol>>3) ^ (lrow&15)) << 3) + (lcol&7)]
                        = (__bf16)acc[i][j][r];
                }
            }
        __syncthreads();
        const int g = tid >> 4, oct = tid & 15;     // 32 row-groups x 16 octs
        const int gc0 = cbase + oct*8;
        float su[8] = {}, sc[8] = {};
#pragma unroll
        for (int rr = 0; rr < 8; ++rr) {
            const int lrow = g*8 + rr;
            bf16x8 cv = *(const bf16x8*)(lds + lrow*128 +
                                         ((oct ^ (lrow&15)) << 3));
            bf16x8 xv = *(const bf16x8*)(xb + (size_t)(row0 + lrow)*H + gc0);
#pragma unroll
            for (int q = 0; q < 8; ++q) {
                float c = (float)cv[q];
                su[q] += (float)xv[q] * c;
                sc[q] += c;
            }
        }
        float* pf = reinterpret_cast<float*>(lds);
        __syncthreads();
#pragma unroll
        for (int q = 0; q < 8; ++q) {
            pf[g*128 + oct*8 + q]        = su[q];
            pf[4096 + g*128 + oct*8 + q] = sc[q];
        }
        __syncthreads();
        const int col = tid & 127;
        const int rb  = (tid >> 7) & 1;
        const int arr = tid >> 8;
        float s = 0.f;
#pragma unroll
        for (int g2 = 0; g2 < 16; ++g2)
            s += pf[arr*4096 + (rb*16 + g2)*128 + col];
        float* dst = arr ? pCp : pUp;
        dst[(size_t)((row0 >> 7) + rb)*H + cbase + col] = s;
    }
}

// ---- cast f32->bf16: x; pack W_proj segs {Cs,res}; Wd; transpose Wp1 -------
#define XB 8192
#define PB 2048
#define DB 1024
#define TB 256
__global__ void cast_kernel(const float* __restrict__ x,
                            const float* __restrict__ Wp,
                            const float* __restrict__ Wd,
                            __bf16* __restrict__ xb,
                            __bf16* __restrict__ Wpb,
                            __bf16* __restrict__ Wdb,
                            __bf16* __restrict__ Wp1T)
{
    __shared__ __bf16 tlds[64*65];
    const int t = threadIdx.x;
    const int bidx = blockIdx.x;

    if (bidx < XB + PB + DB) {
        const f32x4* src; __bf16* dst; int si, di;
        if (bidx < XB) {
            int i = bidx*256 + t;
            src = (const f32x4*)x;  si = i; dst = xb;  di = i;
        } else if (bidx < XB + PB) {
            int j = (bidx - XB)*256 + t;
            int row = j >> 8, cf = j & 255;
            src = (const f32x4*)Wp; si = (2048 + row)*256 + cf;
            dst = Wpb; di = (1024 + row)*256 + cf;
        } else {
            int j = (bidx - XB - PB)*256 + t;
            src = (const f32x4*)Wd; si = j; dst = Wdb; di = j;
        }
        f32x4 v = src[si];
        bf16x4 o = { (__bf16)v[0], (__bf16)v[1], (__bf16)v[2], (__bf16)v[3] };
        *(bf16x4*)(dst + (size_t)di*4) = o;
    } else {
        int tt = bidx - (XB + PB + DB);
        int ty = tt >> 4, tx = tt & 15;
        int rb = t >> 4, cb = t & 15;
#pragma unroll
        for (int rr = 0; rr < 4; ++rr) {
            int row = rb*4 + rr;
            f32x4 v = *(const f32x4*)(Wp + (size_t)(ty*64 + row)*1024 + tx*64 + cb*4);
#pragma unroll
            for (int q = 0; q < 4; ++q)
                tlds[row*65 + cb*4 + q] = (__bf16)v[q];
        }
        __syncthreads();
#pragma unroll
        for (int rr = 0; rr < 4; ++rr) {
            int kk = rb*4 + rr;
            bf16x4 o = { tlds[(cb*4+0)*65 + kk], tlds[(cb*4+1)*65 + kk],
                         tlds[(cb*4+2)*65 + kk], tlds[(cb*4+3)*65 + kk] };
            *(bf16x4*)(Wp1T + (size_t)(tx*64 + kk)*1024 + ty*64 + cb*4) = o;
        }
    }
}

// ---- final: inline chunk-prefix + partial-sum gather + elementwise combine --
__global__ __launch_bounds__(128) void final_kernel(
                             const __bf16* __restrict__ delta,
                             const __bf16* __restrict__ res,
                             const float* __restrict__ pD,   // [512][1024]
                             const float* __restrict__ pUp,  // [64][1024]
                             const float* __restrict__ pCp,  // [64][1024]
                             const float* __restrict__ Av,
                             const float* __restrict__ Bv,
                             const float* __restrict__ Dv,
                             float* __restrict__ out)
{
    const int c = blockIdx.x, b = blockIdx.z;
    const int h0 = blockIdx.y * 256 + threadIdx.x * 2;
    // exclusive prefix of 16-row chunk sums for this (b, c)
    float run0 = 0.f, run1 = 0.f;
#pragma unroll 4
    for (int cp = 0; cp < c; ++cp) {
        f32x2 v = *(const f32x2*)(pD + (size_t)(b*NCH2 + cp)*H + h0);
        run0 += v[0]; run1 += v[1];
    }
    // uC / Csum from 16 row-block partials
    float uc0 = 0.f, uc1 = 0.f, cs0 = 0.f, cs1 = 0.f;
#pragma unroll
    for (int i = 0; i < 16; ++i) {
        f32x2 u = *(const f32x2*)(pUp + (b*16 + i)*H + h0);
        f32x2 s = *(const f32x2*)(pCp + (b*16 + i)*H + h0);
        uc0 += u[0]; uc1 += u[1]; cs0 += s[0]; cs1 += s[1];
    }
    const f32x2 a1 = *(const f32x2*)(Av + h0);
    const f32x2 b1 = *(const f32x2*)(Bv + h0);
    const float dd = Dv[0];
    size_t base = ((size_t)(b*LSEQ + c*LCH2)) * H + h0;
#pragma unroll 4
    for (int l = 0; l < LCH2; ++l) {
        size_t idx = base + (size_t)l * H;
        bf16x2 dv2 = *(const bf16x2*)(delta + idx);
        bf16x2 rs2 = *(const bf16x2*)(res + idx);
        float d0 = (float)dv2[0], d1v = (float)dv2[1];
        run0 += d0; run1 += d1v;
        f32x2 o;
        o[0] = __expf(d0*a1[0])*b1[0]*uc0 + run0*b1[0]*cs0 + (float)rs2[0]*dd;
        o[1] = __expf(d1v*a1[1])*b1[1]*uc1 + run1*b1[1]*cs1 + (float)rs2[1]*dd;
        *(f32x2*)(out + idx) = o;
    }
}

extern "C" void kernel_launch(void* const* d_in, const int* in_sizes, int n_in,
                              void* d_out, int out_size, void* d_ws, size_t ws_size,
                              hipStream_t stream)
{
    (void)in_sizes; (void)n_in; (void)out_size; (void)ws_size;
    const float* x  = (const float*)d_in[0];
    const float* Wp = (const float*)d_in[1];
    const float* Av = (const float*)d_in[2];
    const float* Bv = (const float*)d_in[3];
    const float* Dv = (const float*)d_in[4];
    const float* Wd = (const float*)d_in[5];
    const float* bd = (const float*)d_in[6];
    float* out = (float*)d_out;

    char* ws = (char*)d_ws;
    size_t o = 0;
    auto alloc = [&](size_t bytes) {
        void* p = ws + o; o += (bytes + 255) & ~(size_t)255; return p;
    };
    __bf16* xb   = (__bf16*)alloc((size_t)M_TOT * H * 2);
    __bf16* Wpb  = (__bf16*)alloc((size_t)3072 * H * 2);
    __bf16* Wdb  = (__bf16*)alloc((size_t)H * H * 2);
    __bf16* Wp1T = (__bf16*)alloc((size_t)H * H * 2);
    __bf16* resb = (__bf16*)alloc((size_t)M_TOT * H * 2);
    __bf16* db   = (__bf16*)alloc((size_t)M_TOT * H * 2);
    float*  pD   = (float*)alloc((size_t)BSZ * NCH2 * H * 4);  // 2 MB
    float*  pUp  = (float*)alloc((size_t)64 * H * 4);
    float*  pCp  = (float*)alloc((size_t)64 * H * 4);

    cast_kernel<<<XB + PB + DB + TB, 256, 0, stream>>>(
        x, Wp, Wd, xb, Wpb, Wdb, Wp1T);
    // Wfuse = Wd @ Wp1  -> Wpb rows 0..1023 (full-machine 64x64 tiles)
    wfuse_gemm<<<dim3(16, 16), 256, 0, stream>>>(Wdb, Wp1T, Wpb);
    // Big GEMM: [8192,1024] @ [3072,1024]^T, A via 3-buffer LDS, B via L2
    gemm256b<<<dim3(768), 512, 0, stream>>>(
        xb, Wpb, db, resb, xb, bd, pD, pUp, pCp);
    final_kernel<<<dim3(NCH2, 4, BSZ), 128, 0, stream>>>(db, resb, pD, pUp, pCp,
                                                         Av, Bv, Dv, out);
}

// Round 9
// 192.765 us; speedup vs baseline: 1.3933x; 1.3933x over previous
//
#include <hip/hip_runtime.h>
#include <hip/hip_bf16.h>
#include <cstdint>

#define H 1024
#define BSZ 4
#define LSEQ 2048
#define M_TOT (BSZ*LSEQ)   // 8192
#define NCH2 128           // 16-row L-chunks per batch for the delta scan
#define LCH2 16

typedef __attribute__((ext_vector_type(4))) float  f32x4;
typedef __attribute__((ext_vector_type(2))) float  f32x2;
typedef __attribute__((ext_vector_type(8))) __bf16 bf16x8;
typedef __attribute__((ext_vector_type(4))) __bf16 bf16x4;
typedef __attribute__((ext_vector_type(2))) __bf16 bf16x2;

typedef __attribute__((address_space(1))) unsigned int as1_u32;
typedef __attribute__((address_space(3))) unsigned int as3_u32;

__device__ __forceinline__ void gld_lds16(const void* g, const void* l) {
    as1_u32* gp = reinterpret_cast<as1_u32*>((uintptr_t)g);
    as3_u32* lp = reinterpret_cast<as3_u32*>((uint32_t)(uintptr_t)l);
    __builtin_amdgcn_global_load_lds(gp, lp, 16, 0, 0);
}

// fast softplus: stable, native exp/log
__device__ __forceinline__ float softplus_fast(float f) {
    return fmaxf(f, 0.f) + __logf(1.f + __expf(-fabsf(f)));
}

#define BAR()    asm volatile("s_barrier" ::: "memory")
#define WAIT6()  asm volatile("s_waitcnt vmcnt(6)" ::: "memory")
#define WAIT0()  asm volatile("s_waitcnt vmcnt(0)" ::: "memory")

// ---------------- Wfuse = Wd @ Wp1 : 64x64 tiles, 256 blocks ----------------
__global__ __launch_bounds__(256) void wfuse_gemm(
    const __bf16* __restrict__ A,
    const __bf16* __restrict__ B,
    __bf16* __restrict__ O)
{
    __shared__ __align__(16) __bf16 lds[2*4096];
    const int tid  = threadIdx.x;
    const int lane = tid & 63;
    const int wid  = tid >> 6;
    const int l15  = lane & 15;
    const int quad = lane >> 4;
    const int row0 = blockIdx.y * 64;
    const int col0 = blockIdx.x * 64;

    const __bf16* Asrc = A + (size_t)(row0 + (tid >> 2)) * 1024 + (tid & 3) * 8;
    const __bf16* Bsrc = B + (size_t)(col0 + (tid >> 2)) * 1024 + (tid & 3) * 8;
    const int ldst = (tid >> 2) * 32 + (tid & 3) * 8;   // = tid*8 (linear)

    auto stage = [&](int buf, int kt) {
        gld_lds16(Asrc + kt * 32, lds + buf * 4096 + ldst);
        gld_lds16(Bsrc + kt * 32, lds + buf * 4096 + 2048 + ldst);
    };

    f32x4 acc[4] = {};
    stage(0, 0);
#pragma unroll 2
    for (int kt = 0; kt < 32; ++kt) {
        __syncthreads();                         // implicit vmcnt/lgkm drain
        if (kt + 1 < 32) stage((kt + 1) & 1, kt + 1);
        const __bf16* base = lds + (kt & 1) * 4096;
        bf16x8 a = *(const bf16x8*)(base + (wid * 16 + l15) * 32 + quad * 8);
        bf16x8 b[4];
#pragma unroll
        for (int j = 0; j < 4; ++j)
            b[j] = *(const bf16x8*)(base + 2048 + (j * 16 + l15) * 32 + quad * 8);
#pragma unroll
        for (int j = 0; j < 4; ++j)
            acc[j] = __builtin_amdgcn_mfma_f32_16x16x32_bf16(a, b[j], acc[j], 0, 0, 0);
    }

    const int rowb = row0 + wid * 16 + quad * 4;
#pragma unroll
    for (int j = 0; j < 4; ++j) {
        const int col = col0 + j * 16 + l15;
#pragma unroll
        for (int r = 0; r < 4; ++r)
            O[(size_t)(rowb + r) * H + col] = (__bf16)acc[j][r];
    }
}

// ---------------- BIG GEMM: 256x128 tile, BK=64, 3-buffer, 768 blocks -------
// R5-verified structure (best measured: 61.4-63.6 us GEMM, 192.9 us total).
// ONE barrier per K-tile: all 16 ds_read_b128 + STAGE6 issue inside the same
// barrier section as the 32 MFMAs (two 8-read -> 16-MFMA clusters), so wave
// skew pipelines the LDS port against the matrix pipes.
// Correctness with 1 barrier/tile: 3-buffer rotation -> stage target
// (t+2)%3 disjoint from read buf t%3 and (t+1)%3; tile-entry barrier bounds
// skew to <1 tile, so no wave can stage into a buffer others still read.
// Per-wave counted wait WAIT6 retires exactly this tile's 6 staging loads
// before the barrier (each wave stages 6/tile; 12 in flight steady-state).
// Session brackets (do not revisit): deeper phases (R1), hetero grid /
// 128x64 waves (R3), K-split waves (R6), B-bypass-LDS (R8: uncoalesced,
// lanes stride 2KB -> 64 txn/load) -- all regressed 12-110%.

#define STA(b,u,kt) gld_lds16(Asrc + (size_t)((u)*64)*H + (kt)*64, \
                              lds + (b)*24576 + (u)*4096 + lwb)
#define STB(b,u,kt) gld_lds16(Bsrc + (size_t)((u)*64)*H + (kt)*64, \
                              lds + (b)*24576 + 16384 + (u)*4096 + lwb)
#define STAGE6(b,kt) do { STA(b,0,kt); STA(b,1,kt); STA(b,2,kt); STA(b,3,kt); \
                          STB(b,0,kt); STB(b,1,kt); } while(0)

#define TILE(bc,bn,kn,DS,WAITMAC) do {                                        \
    WAITMAC();                                                                \
    BAR();                                                                    \
    { const __bf16* base_ = lds + (bc)*24576;                                 \
      _Pragma("unroll")                                                       \
      for (int i_ = 0; i_ < 4; ++i_) {                                        \
          af0[i_] = *(const bf16x8*)(base_ + aoff[i_]);                       \
          bf0[i_] = *(const bf16x8*)(base_ + boff[i_]);                       \
      }                                                                       \
      _Pragma("unroll")                                                       \
      for (int i_ = 0; i_ < 4; ++i_) {                                        \
          af1[i_] = *(const bf16x8*)(base_ + (aoff[i_] ^ 32));                \
          bf1[i_] = *(const bf16x8*)(base_ + (boff[i_] ^ 32));                \
      } }                                                                     \
    if (DS) STAGE6(bn, kn);                                                   \
    __builtin_amdgcn_s_setprio(1);                                            \
    _Pragma("unroll")                                                         \
    for (int i_ = 0; i_ < 4; ++i_)                                            \
    _Pragma("unroll")                                                         \
    for (int j_ = 0; j_ < 4; ++j_)                                            \
        acc[i_][j_] = __builtin_amdgcn_mfma_f32_16x16x32_bf16(                \
            af0[i_], bf0[j_], acc[i_][j_], 0, 0, 0);                          \
    _Pragma("unroll")                                                         \
    for (int i_ = 0; i_ < 4; ++i_)                                            \
    _Pragma("unroll")                                                         \
    for (int j_ = 0; j_ < 4; ++j_)                                            \
        acc[i_][j_] = __builtin_amdgcn_mfma_f32_16x16x32_bf16(                \
            af1[i_], bf1[j_], acc[i_][j_], 0, 0, 0);                          \
    __builtin_amdgcn_s_setprio(0);                                            \
} while(0)

__global__ __launch_bounds__(512, 2) void gemm256b(
    const __bf16* __restrict__ A,
    const __bf16* __restrict__ B,
    __bf16* __restrict__ O0,
    __bf16* __restrict__ O2,
    const __bf16* __restrict__ xb,
    const float* __restrict__ bias,
    float* __restrict__ pD,     // [512][1024] 16-row chunk col sums
    float* __restrict__ pUp,    // [64][1024] partial sum(x*Cs) per 128-row blk
    float* __restrict__ pCp)    // [64][1024] partial sum(Cs)
{
    __shared__ __align__(16) __bf16 lds[73728];   // 144 KiB: 3 x (16K A + 8K B)

    const int tid  = threadIdx.x;
    const int lane = tid & 63;
    const int wid  = tid >> 6;
    const int l15  = lane & 15;
    const int quad = lane >> 4;
    const int wrv  = (wid >> 1) * 64;   // 4 M-strips of 64 rows
    const int wcv  = (wid & 1) * 64;    // 2 N-strips of 64 cols

    // XCD-bijective swizzle: 768 blocks, 768 % 8 == 0
    const int bid = blockIdx.x;
    const int swz = (bid & 7) * 96 + (bid >> 3);
    const int bx = swz % 24;            // 24 col-blocks of 128
    const int by = swz / 24;            // 32 row-blocks of 256
    const int row0 = by * 256;
    const int col0 = bx * 128;

    // staging: pre-swizzled global granule, linear LDS dest (rule 21)
    const int lg = (tid & 7) ^ ((tid >> 3) & 7);
    const __bf16* Asrc = A + (size_t)(row0 + (tid >> 3)) * H + lg * 8;
    const __bf16* Bsrc = B + (size_t)(col0 + (tid >> 3)) * H + lg * 8;
    const int lwb = wid * 512;          // wave-uniform LDS base (elements)

    int aoff[4], boff[4];
#pragma unroll
    for (int i = 0; i < 4; ++i)
        aoff[i] = (wrv + i*16 + l15)*64 + ((quad ^ (l15 & 7)) << 3);
#pragma unroll
    for (int j = 0; j < 4; ++j)
        boff[j] = 16384 + (wcv + j*16 + l15)*64 + ((quad ^ (l15 & 7)) << 3);

    f32x4 acc[4][4] = {};
    bf16x8 af0[4], bf0[4], af1[4], bf1[4];

    STAGE6(0, 0);
    STAGE6(1, 1);

#pragma unroll 1
    for (int g = 0; g < 4; ++g) {
        TILE(0, 2, 3*g + 2, 1, WAIT6);
        TILE(1, 0, 3*g + 3, 1, WAIT6);
        TILE(2, 1, 3*g + 4, 1, WAIT6);
    }
    TILE(0, 2, 14, 1, WAIT6);   // t12
    TILE(1, 0, 15, 1, WAIT6);   // t13
    TILE(2, 0,  0, 0, WAIT6);   // t14 (no stage)
    TILE(0, 0,  0, 0, WAIT0);   // t15 (no stage, drain)
    __syncthreads();

    // ---------------- epilogue ----------------
    const int seg   = col0 >> 10;
    const int cbase = col0 & 1023;
    const int colb  = cbase + wcv + l15;
    const int rowb  = row0 + wrv + quad*4;

    if (seg == 0) {
        // delta: bias + softplus + store + per-16-row-chunk col sums
        const int chunk16 = (row0 + wrv) >> 4;   // global 16-row chunk base
#pragma unroll
        for (int j = 0; j < 4; ++j) {
            const int col = colb + j*16;
            const float bv = bias[col];
#pragma unroll
            for (int i = 0; i < 4; ++i) {
                float s = 0.f;
#pragma unroll
                for (int r = 0; r < 4; ++r) {
                    float f = softplus_fast(acc[i][j][r] + bv);
                    O0[(size_t)(rowb + i*16 + r) * H + col] = (__bf16)f;
                    s += f;
                }
                s += __shfl_down(s, 32); s += __shfl_down(s, 16);
                if (quad == 0) pD[(size_t)(chunk16 + i)*H + col] = s;
            }
        }
    } else if (seg == 2) {
        // residual: plain store
#pragma unroll
        for (int i = 0; i < 4; ++i)
#pragma unroll
            for (int j = 0; j < 4; ++j) {
                const int col = colb + j*16;
#pragma unroll
                for (int r = 0; r < 4; ++r)
                    O2[(size_t)(rowb + i*16 + r) * H + col] = (__bf16)acc[i][j][r];
            }
    } else {
        // Cs: 256x128 tile -> LDS (granule-XOR), coalesced reduce with xb,
        // cross-group reduce -> pUp/pCp[64][1024] (per-128-row partials).
#pragma unroll
        for (int i = 0; i < 4; ++i)
#pragma unroll
            for (int j = 0; j < 4; ++j) {
                const int lcol = wcv + j*16 + l15;
#pragma unroll
                for (int r = 0; r < 4; ++r) {
                    const int lrow = wrv + i*16 + quad*4 + r;
                    lds[lrow*128 + (((lcol>>3) ^ (lrow&15)) << 3) + (lcol&7)]
                        = (__bf16)acc[i][j][r];
                }
            }
        __syncthreads();
        const int g = tid >> 4, oct = tid & 15;     // 32 row-groups x 16 octs
        const int gc0 = cbase + oct*8;
        float su[8] = {}, sc[8] = {};
#pragma unroll
        for (int rr = 0; rr < 8; ++rr) {
            const int lrow = g*8 + rr;
            bf16x8 cv = *(const bf16x8*)(lds + lrow*128 +
                                         ((oct ^ (lrow&15)) << 3));
            bf16x8 xv = *(const bf16x8*)(xb + (size_t)(row0 + lrow)*H + gc0);
#pragma unroll
            for (int q = 0; q < 8; ++q) {
                float c = (float)cv[q];
                su[q] += (float)xv[q] * c;
                sc[q] += c;
            }
        }
        float* pf = reinterpret_cast<float*>(lds);
        __syncthreads();
#pragma unroll
        for (int q = 0; q < 8; ++q) {
            pf[g*128 + oct*8 + q]        = su[q];
            pf[4096 + g*128 + oct*8 + q] = sc[q];
        }
        __syncthreads();
        const int col = tid & 127;
        const int rb  = (tid >> 7) & 1;
        const int arr = tid >> 8;
        float s = 0.f;
#pragma unroll
        for (int g2 = 0; g2 < 16; ++g2)
            s += pf[arr*4096 + (rb*16 + g2)*128 + col];
        float* dst = arr ? pCp : pUp;
        dst[(size_t)((row0 >> 7) + rb)*H + cbase + col] = s;
    }
}

// ---- cast f32->bf16: x; pack W_proj segs {Cs,res}; Wd; transpose Wp1 -------
#define XB 8192
#define PB 2048
#define DB 1024
#define TB 256
__global__ void cast_kernel(const float* __restrict__ x,
                            const float* __restrict__ Wp,
                            const float* __restrict__ Wd,
                            __bf16* __restrict__ xb,
                            __bf16* __restrict__ Wpb,
                            __bf16* __restrict__ Wdb,
                            __bf16* __restrict__ Wp1T)
{
    __shared__ __bf16 tlds[64*65];
    const int t = threadIdx.x;
    const int bidx = blockIdx.x;

    if (bidx < XB + PB + DB) {
        const f32x4* src; __bf16* dst; int si, di;
        if (bidx < XB) {
            int i = bidx*256 + t;
            src = (const f32x4*)x;  si = i; dst = xb;  di = i;
        } else if (bidx < XB + PB) {
            int j = (bidx - XB)*256 + t;
            int row = j >> 8, cf = j & 255;
            src = (const f32x4*)Wp; si = (2048 + row)*256 + cf;
            dst = Wpb; di = (1024 + row)*256 + cf;
        } else {
            int j = (bidx - XB - PB)*256 + t;
            src = (const f32x4*)Wd; si = j; dst = Wdb; di = j;
        }
        f32x4 v = src[si];
        bf16x4 o = { (__bf16)v[0], (__bf16)v[1], (__bf16)v[2], (__bf16)v[3] };
        *(bf16x4*)(dst + (size_t)di*4) = o;
    } else {
        int tt = bidx - (XB + PB + DB);
        int ty = tt >> 4, tx = tt & 15;
        int rb = t >> 4, cb = t & 15;
#pragma unroll
        for (int rr = 0; rr < 4; ++rr) {
            int row = rb*4 + rr;
            f32x4 v = *(const f32x4*)(Wp + (size_t)(ty*64 + row)*1024 + tx*64 + cb*4);
#pragma unroll
            for (int q = 0; q < 4; ++q)
                tlds[row*65 + cb*4 + q] = (__bf16)v[q];
        }
        __syncthreads();
#pragma unroll
        for (int rr = 0; rr < 4; ++rr) {
            int kk = rb*4 + rr;
            bf16x4 o = { tlds[(cb*4+0)*65 + kk], tlds[(cb*4+1)*65 + kk],
                         tlds[(cb*4+2)*65 + kk], tlds[(cb*4+3)*65 + kk] };
            *(bf16x4*)(Wp1T + (size_t)(tx*64 + kk)*1024 + ty*64 + cb*4) = o;
        }
    }
}

// ---- final: inline chunk-prefix + partial-sum gather + elementwise combine --
__global__ __launch_bounds__(128) void final_kernel(
                             const __bf16* __restrict__ delta,
                             const __bf16* __restrict__ res,
                             const float* __restrict__ pD,   // [512][1024]
                             const float* __restrict__ pUp,  // [64][1024]
                             const float* __restrict__ pCp,  // [64][1024]
                             const float* __restrict__ Av,
                             const float* __restrict__ Bv,
                             const float* __restrict__ Dv,
                             float* __restrict__ out)
{
    const int c = blockIdx.x, b = blockIdx.z;
    const int h0 = blockIdx.y * 256 + threadIdx.x * 2;
    // exclusive prefix of 16-row chunk sums for this (b, c)
    float run0 = 0.f, run1 = 0.f;
#pragma unroll 4
    for (int cp = 0; cp < c; ++cp) {
        f32x2 v = *(const f32x2*)(pD + (size_t)(b*NCH2 + cp)*H + h0);
        run0 += v[0]; run1 += v[1];
    }
    // uC / Csum from 16 row-block partials
    float uc0 = 0.f, uc1 = 0.f, cs0 = 0.f, cs1 = 0.f;
#pragma unroll
    for (int i = 0; i < 16; ++i) {
        f32x2 u = *(const f32x2*)(pUp + (b*16 + i)*H + h0);
        f32x2 s = *(const f32x2*)(pCp + (b*16 + i)*H + h0);
        uc0 += u[0]; uc1 += u[1]; cs0 += s[0]; cs1 += s[1];
    }
    const f32x2 a1 = *(const f32x2*)(Av + h0);
    const f32x2 b1 = *(const f32x2*)(Bv + h0);
    const float dd = Dv[0];
    size_t base = ((size_t)(b*LSEQ + c*LCH2)) * H + h0;
#pragma unroll 4
    for (int l = 0; l < LCH2; ++l) {
        size_t idx = base + (size_t)l * H;
        bf16x2 dv2 = *(const bf16x2*)(delta + idx);
        bf16x2 rs2 = *(const bf16x2*)(res + idx);
        float d0 = (float)dv2[0], d1v = (float)dv2[1];
        run0 += d0; run1 += d1v;
        f32x2 o;
        o[0] = __expf(d0*a1[0])*b1[0]*uc0 + run0*b1[0]*cs0 + (float)rs2[0]*dd;
        o[1] = __expf(d1v*a1[1])*b1[1]*uc1 + run1*b1[1]*cs1 + (float)rs2[1]*dd;
        *(f32x2*)(out + idx) = o;
    }
}

extern "C" void kernel_launch(void* const* d_in, const int* in_sizes, int n_in,
                              void* d_out, int out_size, void* d_ws, size_t ws_size,
                              hipStream_t stream)
{
    (void)in_sizes; (void)n_in; (void)out_size; (void)ws_size;
    const float* x  = (const float*)d_in[0];
    const float* Wp = (const float*)d_in[1];
    const float* Av = (const float*)d_in[2];
    const float* Bv = (const float*)d_in[3];
    const float* Dv = (const float*)d_in[4];
    const float* Wd = (const float*)d_in[5];
    const float* bd = (const float*)d_in[6];
    float* out = (float*)d_out;

    char* ws = (char*)d_ws;
    size_t o = 0;
    auto alloc = [&](size_t bytes) {
        void* p = ws + o; o += (bytes + 255) & ~(size_t)255; return p;
    };
    __bf16* xb   = (__bf16*)alloc((size_t)M_TOT * H * 2);
    __bf16* Wpb  = (__bf16*)alloc((size_t)3072 * H * 2);
    __bf16* Wdb  = (__bf16*)alloc((size_t)H * H * 2);
    __bf16* Wp1T = (__bf16*)alloc((size_t)H * H * 2);
    __bf16* resb = (__bf16*)alloc((size_t)M_TOT * H * 2);
    __bf16* db   = (__bf16*)alloc((size_t)M_TOT * H * 2);
    float*  pD   = (float*)alloc((size_t)BSZ * NCH2 * H * 4);  // 2 MB
    float*  pUp  = (float*)alloc((size_t)64 * H * 4);
    float*  pCp  = (float*)alloc((size_t)64 * H * 4);

    cast_kernel<<<XB + PB + DB + TB, 256, 0, stream>>>(
        x, Wp, Wd, xb, Wpb, Wdb, Wp1T);
    // Wfuse = Wd @ Wp1  -> Wpb rows 0..1023 (full-machine 64x64 tiles)
    wfuse_gemm<<<dim3(16, 16), 256, 0, stream>>>(Wdb, Wp1T, Wpb);
    // Big GEMM: [8192,1024] @ [3072,1024]^T, 256x128 3-buffer, 768 blocks
    gemm256b<<<dim3(768), 512, 0, stream>>>(
        xb, Wpb, db, resb, xb, bd, pD, pUp, pCp);
    final_kernel<<<dim3(NCH2, 4, BSZ), 128, 0, stream>>>(db, resb, pD, pUp, pCp,
                                                         Av, Bv, Dv, out);
}